// Round 9
// baseline (23.377 us; speedup 1.0000x reference)
//
#include <hip/hip_runtime.h>

// KAConv: out[b,f,h,w] = sum_{c,p} P_fcp(v) / (1 + |Q_fcp(v)|),
//   v = x[b,c,h+i-1,w+j-1] (zero pad), p = i*3+j
// Shapes: x[4,16,64,64], A[16,16,9,6], Bc[16,16,9,4], out[4,16,64,64], f32.
//
// Round 9: amortize PER-WAVE fixed costs (r8 falsified the scalar-stall
// theory: resident coeffs gave identical 20 us). Each wave now runs ~8x
// longer: 2 channels (wid, wid+8) x 8 rows x 64 cols, with all 30 window
// values per half loaded upfront (ONE vmcnt wait per half), one barrier per
// kernel, 4 blocks-deep pipelining per CU. Adjacent taps are PAIRED over a
// common denominator (P1/d1 + P2/d2 = (P1*d2+P2*d1)/(d1*d2)) halving the
// quarter-rate v_rcp count 9 -> 5 per pixel-channel.

#define BB   4
#define CIN  16
#define COUT 16
#define HH   64
#define WW   64

// One rational tap: P(v) and d = 1 + |q(v)|. p is compile-time after unroll,
// so Ac/Bq reads are uniform constant-offset -> s_load, hoisted per half.
static __device__ __forceinline__ void rat(const float* __restrict__ Ac,
                                           const float* __restrict__ Bq,
                                           int p, float v, float& P, float& d)
{
    const float a0 = Ac[p*6+0], a1 = Ac[p*6+1], a2 = Ac[p*6+2];
    const float a3 = Ac[p*6+3], a4 = Ac[p*6+4], a5 = Ac[p*6+5];
    const float b1 = Bq[p*4+0], b2 = Bq[p*4+1], b3 = Bq[p*4+2], b4 = Bq[p*4+3];
    float Pp = a5;
    Pp = fmaf(Pp, v, a4); Pp = fmaf(Pp, v, a3); Pp = fmaf(Pp, v, a2);
    Pp = fmaf(Pp, v, a1); Pp = fmaf(Pp, v, a0);
    float q = b4;
    q = fmaf(q, v, b3); q = fmaf(q, v, b2); q = fmaf(q, v, b1);
    q *= v;
    P = Pp;
    d = 1.0f + fabsf(q);
}

__global__ __launch_bounds__(512, 4) void KAConv_kernel(
    const float* __restrict__ x,    // [B,C,H,W]
    const float* __restrict__ A,    // [F,C,9,6]
    const float* __restrict__ Bc,   // [F,C,9,4]
    float* __restrict__ out)        // [B,F,H,W]
{
    // grid = b(4) x rowgroup(8) x f(16) = 512 blocks; block = 512 = 8 waves.
    const int blk = blockIdx.x;
    const int f   = blk & 15;
    const int rg  = (blk >> 4) & 7;
    const int b   = blk >> 7;

    const int tid   = threadIdx.x;
    const int wid   = __builtin_amdgcn_readfirstlane(tid >> 6);  // 0..7
    const int lane  = tid & 63;
    const int w     = lane;
    const int rbase = rg << 3;            // rows rbase..rbase+7

    __shared__ float sRed[8][512];        // 16 KB

    float acc[8];
    #pragma unroll
    for (int i = 0; i < 8; ++i) acc[i] = 0.0f;

    #pragma unroll 1
    for (int half = 0; half < 2; ++half) {
        const int c = wid + (half << 3);
        const float* __restrict__ Ac = A  + (f * CIN + c) * 54;
        const float* __restrict__ Bq = Bc + (f * CIN + c) * 36;
        const float* __restrict__ xc = x  + (b * CIN + c) * (HH * WW);

        // All 10 window rows (rbase-1 .. rbase+8) x 3 col offsets upfront:
        // 30 loads, one vmcnt wait. Row bounds are wave-uniform (scalar).
        float win[10][3];
        #pragma unroll
        for (int r = 0; r < 10; ++r) {
            const int hh   = rbase - 1 + r;
            const bool okh = (hh >= 0) & (hh < HH);
            #pragma unroll
            for (int j = 0; j < 3; ++j) {
                const int wj  = w + j - 1;
                const bool ok = okh & (wj >= 0) & (wj < WW);
                win[r][j] = ok ? xc[hh * WW + wj] : 0.0f;
            }
        }

        #pragma unroll
        for (int rp = 0; rp < 4; ++rp) {
            #pragma unroll
            for (int px = 0; px < 2; ++px) {
                float aloc = 0.0f;
                // taps 0..7 as 4 common-denominator pairs
                #pragma unroll
                for (int pp = 0; pp < 4; ++pp) {
                    const int pA = 2 * pp, pB = 2 * pp + 1;
                    const float vA = win[(rp << 1) + px + pA / 3][pA % 3];
                    const float vB = win[(rp << 1) + px + pB / 3][pB % 3];
                    float PA, dA, PB, dB;
                    rat(Ac, Bq, pA, vA, PA, dA);
                    rat(Ac, Bq, pB, vB, PB, dB);
                    float num = PA * dB;
                    num = fmaf(PB, dA, num);
                    const float den = dA * dB;
                    aloc = fmaf(num, __builtin_amdgcn_rcpf(den), aloc);
                }
                // tap 8 (unpaired)
                {
                    const float v8 = win[(rp << 1) + px + 2][2];
                    float P8, d8;
                    rat(Ac, Bq, 8, v8, P8, d8);
                    aloc = fmaf(P8, __builtin_amdgcn_rcpf(d8), aloc);
                }
                acc[(rp << 1) + px] += aloc;
            }
        }
    }

    // One barrier per kernel: dump 8 rows/lane, sum 8 channel-waves, store.
    #pragma unroll
    for (int rl = 0; rl < 8; ++rl)
        sRed[wid][rl * 64 + lane] = acc[rl];   // consecutive per lane: conflict-free
    __syncthreads();

    {
        float s = 0.0f;
        #pragma unroll
        for (int k = 0; k < 8; ++k) s += sRed[k][tid];   // consecutive per wave: conflict-free
        const int rl  = tid >> 6;
        const int col = tid & 63;
        out[((b * COUT + f) * HH + rbase + rl) * WW + col] = s;
    }
}

extern "C" void kernel_launch(void* const* d_in, const int* in_sizes, int n_in,
                              void* d_out, int out_size, void* d_ws, size_t ws_size,
                              hipStream_t stream) {
    const float* x  = (const float*)d_in[0];
    const float* A  = (const float*)d_in[1];
    const float* Bc = (const float*)d_in[2];
    float* out = (float*)d_out;

    const int grid = BB * (HH / 8) * COUT;   // 512 blocks
    KAConv_kernel<<<grid, 512, 0, stream>>>(x, A, Bc, out);
}